// Round 1
// baseline (456.195 us; speedup 1.0000x reference)
//
#include <hip/hip_runtime.h>
#include <hip/hip_bf16.h>

#define NSEG 50000

typedef __attribute__((ext_vector_type(4))) float f32x4;
typedef __attribute__((ext_vector_type(8))) short s16x8;

static __device__ __forceinline__ unsigned short f2bf(float f) {
  unsigned int u = __float_as_uint(f);
  u += 0x7fffu + ((u >> 16) & 1u);   // round-to-nearest-even
  return (unsigned short)(u >> 16);
}

// ---------------------------------------------------------------------------
// prep: w_src[h,k] = sum_f W[h*32+f,k]*a_src[h,f]; w_tgt likewise.
//       Wb = bf16(W). denom = 0.
// ---------------------------------------------------------------------------
__global__ __launch_bounds__(256) void prep_kernel(
    const float* __restrict__ W, const float* __restrict__ a_src,
    const float* __restrict__ a_tgt, float* __restrict__ w_src,
    float* __restrict__ w_tgt, unsigned short* __restrict__ Wb,
    float* __restrict__ denom) {
  int t = blockIdx.x * 256 + threadIdx.x;
  if (t < 32768) Wb[t] = f2bf(W[t]);
  if (t < 1024) {
    int h = t >> 7, k = t & 127;
    float as = 0.f, at = 0.f;
    for (int f = 0; f < 32; ++f) {
      float wv = W[(h * 32 + f) * 128 + k];
      as += wv * a_src[h * 32 + f];
      at += wv * a_tgt[h * 32 + f];
    }
    w_src[t] = as;
    w_tgt[t] = at;
  }
  if (t < NSEG * 8) denom[t] = 0.f;
}

// ---------------------------------------------------------------------------
// score: per edge, 16 fp32 dots of length 128 against w_src/w_tgt (LDS),
// leaky_relu, exp (no max-shift: scores bounded), atomicAdd segment sums.
// ---------------------------------------------------------------------------
__global__ __launch_bounds__(256) void score_kernel(
    const float* __restrict__ msg, const int* __restrict__ index,
    const float* __restrict__ w_src, const float* __restrict__ w_tgt,
    float* __restrict__ ex, float* __restrict__ denom, int n) {
  __shared__ float4 ws[256];  // 8 heads x 32 float4 = 128 floats per head
  __shared__ float4 wt[256];
  int tid = threadIdx.x;
  ws[tid] = ((const float4*)w_src)[tid];
  wt[tid] = ((const float4*)w_tgt)[tid];
  __syncthreads();

  int e = blockIdx.x * 256 + tid;
  if (e >= n) return;

  const float4* ms = (const float4*)(msg + (size_t)e * 128);
  const float4* mt = (const float4*)(msg + ((size_t)e + (size_t)n) * 128);

  float accs[8] = {0.f, 0.f, 0.f, 0.f, 0.f, 0.f, 0.f, 0.f};
  float acct[8] = {0.f, 0.f, 0.f, 0.f, 0.f, 0.f, 0.f, 0.f};

#pragma unroll 2
  for (int k4 = 0; k4 < 32; ++k4) {
    float4 a = ms[k4];
    float4 b = mt[k4];
#pragma unroll
    for (int h = 0; h < 8; ++h) {
      float4 u = ws[h * 32 + k4];
      float4 v = wt[h * 32 + k4];
      accs[h] += a.x * u.x + a.y * u.y + a.z * u.z + a.w * u.w;
      acct[h] += b.x * v.x + b.y * v.y + b.z * v.z + b.w * v.w;
    }
  }

  int seg = index[e];
  float exv[8];
#pragma unroll
  for (int h = 0; h < 8; ++h) {
    float s = accs[h] + acct[h];
    s = s > 0.f ? s : 0.2f * s;   // leaky_relu, NEG_SLOPE=0.2
    float ev = __expf(s);
    exv[h] = ev;
    atomicAdd(&denom[seg * 8 + h], ev);
  }
  float4* eo = (float4*)(ex + (size_t)e * 8);
  eo[0] = make_float4(exv[0], exv[1], exv[2], exv[3]);
  eo[1] = make_float4(exv[4], exv[5], exv[6], exv[7]);
}

// ---------------------------------------------------------------------------
// gemm: proj_tgt = msg_tgt @ W^T via bf16 MFMA 16x16x32, fused epilogue:
//   out[e]      = att[e,h] * proj   (att = ex / (denom[seg]+1e-16))
//   out[n+e]    = proj
// Block = 64 rows x 256 cols, 4 waves each own 16 rows.
// ---------------------------------------------------------------------------
__global__ __launch_bounds__(256) void gemm_kernel(
    const float* __restrict__ msg, const int* __restrict__ index,
    const unsigned short* __restrict__ Wb, const float* __restrict__ ex,
    const float* __restrict__ denom, float* __restrict__ out, int n) {
  __shared__ float att_lds[64][9];
  int tid = threadIdx.x;
  int mbase = blockIdx.x * 64;

  // att for this block's 64 rows x 8 heads
  for (int i = tid; i < 512; i += 256) {
    int r = i >> 3, h = i & 7;
    int ge = mbase + r;
    float a = 0.f;
    if (ge < n) {
      int seg = index[ge];
      a = ex[(size_t)ge * 8 + h] / (denom[seg * 8 + h] + 1e-16f);
    }
    att_lds[r][h] = a;
  }
  __syncthreads();

  int w = tid >> 6, l = tid & 63;
  int lrow = l & 15;       // M index within 16x16 tile
  int kgrp = l >> 4;       // 0..3, covers k-chunk of 8
  int grow = mbase + w * 16 + lrow;
  int ga = grow < n ? grow : n - 1;
  const float* arow = msg + ((size_t)ga + (size_t)n) * 128;  // msg_tgt row

  // A fragments: 4 K-steps of 32, lane holds 8 contiguous bf16 along K
  s16x8 afrag[4];
#pragma unroll
  for (int kk = 0; kk < 4; ++kk) {
    int k0 = kk * 32 + kgrp * 8;
    float4 p0 = *(const float4*)(arow + k0);
    float4 p1 = *(const float4*)(arow + k0 + 4);
    s16x8 af;
    af[0] = (short)f2bf(p0.x); af[1] = (short)f2bf(p0.y);
    af[2] = (short)f2bf(p0.z); af[3] = (short)f2bf(p0.w);
    af[4] = (short)f2bf(p1.x); af[5] = (short)f2bf(p1.y);
    af[6] = (short)f2bf(p1.z); af[7] = (short)f2bf(p1.w);
    afrag[kk] = af;
  }

  // 16 column tiles of 16 (N = 256)
  for (int ct = 0; ct < 16; ++ct) {
    int col = ct * 16 + lrow;
    f32x4 acc = {0.f, 0.f, 0.f, 0.f};
#pragma unroll
    for (int kk = 0; kk < 4; ++kk) {
      s16x8 bfrag = *(const s16x8*)(Wb + (size_t)col * 128 + kk * 32 + kgrp * 8);
      acc = __builtin_amdgcn_mfma_f32_16x16x32_bf16(afrag[kk], bfrag, acc, 0, 0, 0);
    }
    int h = ct >> 1;  // head index (cols 32-wide per head, tiles 16-wide)
#pragma unroll
    for (int r = 0; r < 4; ++r) {
      int lr = w * 16 + kgrp * 4 + r;  // C/D row = (lane>>4)*4 + reg
      int ge = mbase + lr;
      if (ge < n) {
        float p = acc[r];
        float a = att_lds[lr][h];
        out[(size_t)ge * 256 + col] = a * p;
        out[((size_t)ge + (size_t)n) * 256 + col] = p;
      }
    }
  }
}

// ---------------------------------------------------------------------------
extern "C" void kernel_launch(void* const* d_in, const int* in_sizes, int n_in,
                              void* d_out, int out_size, void* d_ws, size_t ws_size,
                              hipStream_t stream) {
  const float* messages = (const float*)d_in[0];
  const float* W        = (const float*)d_in[1];
  const float* a_src    = (const float*)d_in[2];
  const float* a_tgt    = (const float*)d_in[3];
  const int*   index    = (const int*)d_in[4];
  int n = in_sizes[4];  // n_edges = 250000

  char* ws = (char*)d_ws;
  float* w_src          = (float*)(ws);
  float* w_tgt          = (float*)(ws + 4096);
  unsigned short* Wb    = (unsigned short*)(ws + 8192);
  float* denom          = (float*)(ws + 8192 + 65536);
  float* ex             = (float*)(ws + 8192 + 65536 + 1600000);
  float* out = (float*)d_out;

  prep_kernel<<<(NSEG * 8 + 255) / 256, 256, 0, stream>>>(W, a_src, a_tgt, w_src,
                                                          w_tgt, Wb, denom);
  score_kernel<<<(n + 255) / 256, 256, 0, stream>>>(messages, index, w_src, w_tgt,
                                                    ex, denom, n);
  gemm_kernel<<<(n + 63) / 64, 256, 0, stream>>>(messages, index, Wb, ex, denom,
                                                 out, n);
}

// Round 2
// 346.555 us; speedup vs baseline: 1.3164x; 1.3164x over previous
//
#include <hip/hip_runtime.h>
#include <hip/hip_bf16.h>

#define NSEG 50000

typedef __attribute__((ext_vector_type(4))) float f32x4;
typedef __attribute__((ext_vector_type(8))) short s16x8;

static __device__ __forceinline__ unsigned short f2bf(float f) {
  unsigned int u = __float_as_uint(f);
  u += 0x7fffu + ((u >> 16) & 1u);   // round-to-nearest-even
  return (unsigned short)(u >> 16);
}

// ---------------------------------------------------------------------------
// prep: Wb = bf16(W) [256x128].
//       wb_cat[16][128] bf16: rows 0-7 = sum_f W[h*32+f,:]*a_src[h,f] (head h),
//                             rows 8-15 = same with a_tgt.
//       denom = 0.
// ---------------------------------------------------------------------------
__global__ __launch_bounds__(256) void prep_kernel(
    const float* __restrict__ W, const float* __restrict__ a_src,
    const float* __restrict__ a_tgt, unsigned short* __restrict__ Wb,
    unsigned short* __restrict__ wb_cat, float* __restrict__ denom) {
  int t = blockIdx.x * 256 + threadIdx.x;
  if (t < 32768) Wb[t] = f2bf(W[t]);
  if (t < 2048) {
    int row = t >> 7, k = t & 127;
    int h = row & 7;
    const float* a = (row < 8) ? a_src : a_tgt;
    float acc = 0.f;
    for (int f = 0; f < 32; ++f) acc += W[(h * 32 + f) * 128 + k] * a[h * 32 + f];
    wb_cat[t] = f2bf(acc);
  }
  if (t < NSEG * 8) denom[t] = 0.f;
}

// ---------------------------------------------------------------------------
// score: MFMA mini-GEMM. Wave owns 16 edges. B = wb_cat (16 cols x 128 K).
//   D_s[row, col] = msg_src[row] . wb_cat[col]   (cols 0-7  = w_src heads)
//   D_t[row, col] = msg_tgt[row] . wb_cat[col]   (cols 8-15 = w_tgt heads)
//   s[e,h] = D_s[e,h] + D_t[e,h+8]  (shfl_xor lane^8 brings col+8)
//   leaky_relu, exp, atomicAdd segment denom, store ex.
// ---------------------------------------------------------------------------
__global__ __launch_bounds__(256) void score_kernel(
    const float* __restrict__ msg, const int* __restrict__ index,
    const unsigned short* __restrict__ wb_cat, float* __restrict__ ex,
    float* __restrict__ denom, int n) {
  int tid = threadIdx.x;
  int w = tid >> 6, l = tid & 63;
  int lrow = l & 15;   // A row / B col within tile
  int kgrp = l >> 4;   // k-chunk of 8
  int e0 = blockIdx.x * 64 + w * 16;
  int grow = e0 + lrow;
  int ga = grow < n ? grow : n - 1;
  const float* rs = msg + (size_t)ga * 128;                   // msg_src row
  const float* rt = msg + ((size_t)ga + (size_t)n) * 128;     // msg_tgt row

  s16x8 bfrag[4];
#pragma unroll
  for (int kk = 0; kk < 4; ++kk)
    bfrag[kk] = *(const s16x8*)(wb_cat + lrow * 128 + kk * 32 + kgrp * 8);

  f32x4 ds_acc = {0.f, 0.f, 0.f, 0.f};
  f32x4 dt_acc = {0.f, 0.f, 0.f, 0.f};
#pragma unroll
  for (int kk = 0; kk < 4; ++kk) {
    int k0 = kk * 32 + kgrp * 8;
    float4 p0 = *(const float4*)(rs + k0);
    float4 p1 = *(const float4*)(rs + k0 + 4);
    s16x8 af;
    af[0] = (short)f2bf(p0.x); af[1] = (short)f2bf(p0.y);
    af[2] = (short)f2bf(p0.z); af[3] = (short)f2bf(p0.w);
    af[4] = (short)f2bf(p1.x); af[5] = (short)f2bf(p1.y);
    af[6] = (short)f2bf(p1.z); af[7] = (short)f2bf(p1.w);
    ds_acc = __builtin_amdgcn_mfma_f32_16x16x32_bf16(af, bfrag[kk], ds_acc, 0, 0, 0);
    float4 q0 = *(const float4*)(rt + k0);
    float4 q1 = *(const float4*)(rt + k0 + 4);
    s16x8 at_;
    at_[0] = (short)f2bf(q0.x); at_[1] = (short)f2bf(q0.y);
    at_[2] = (short)f2bf(q0.z); at_[3] = (short)f2bf(q0.w);
    at_[4] = (short)f2bf(q1.x); at_[5] = (short)f2bf(q1.y);
    at_[6] = (short)f2bf(q1.z); at_[7] = (short)f2bf(q1.w);
    dt_acc = __builtin_amdgcn_mfma_f32_16x16x32_bf16(at_, bfrag[kk], dt_acc, 0, 0, 0);
  }

  // C/D layout: col = l&15, row = kgrp*4 + r
  int col = lrow;
#pragma unroll
  for (int r = 0; r < 4; ++r) {
    float tv = __shfl_xor(dt_acc[r], 8);  // lane with col+8 -> col (and vice versa)
    int ge = e0 + kgrp * 4 + r;
    if (col < 8 && ge < n) {
      float s = ds_acc[r] + tv;
      s = s > 0.f ? s : 0.2f * s;        // leaky_relu, NEG_SLOPE=0.2
      float ev = __expf(s);
      int seg = index[ge];
      atomicAdd(&denom[seg * 8 + col], ev);
      ex[(size_t)ge * 8 + col] = ev;
    }
  }
}

// ---------------------------------------------------------------------------
// gemm: proj_tgt = msg_tgt @ W^T via bf16 MFMA 16x16x32, fused epilogue:
//   out[e]   = att[e,h] * proj   (att = ex / (denom[seg]+1e-16))
//   out[n+e] = proj
// Block = 64 rows x 256 cols, 4 waves each own 16 rows.
// ---------------------------------------------------------------------------
__global__ __launch_bounds__(256) void gemm_kernel(
    const float* __restrict__ msg, const int* __restrict__ index,
    const unsigned short* __restrict__ Wb, const float* __restrict__ ex,
    const float* __restrict__ denom, float* __restrict__ out, int n) {
  __shared__ float att_lds[64][9];
  int tid = threadIdx.x;
  int mbase = blockIdx.x * 64;

  for (int i = tid; i < 512; i += 256) {
    int r = i >> 3, h = i & 7;
    int ge = mbase + r;
    float a = 0.f;
    if (ge < n) {
      int seg = index[ge];
      a = ex[(size_t)ge * 8 + h] / (denom[seg * 8 + h] + 1e-16f);
    }
    att_lds[r][h] = a;
  }
  __syncthreads();

  int w = tid >> 6, l = tid & 63;
  int lrow = l & 15;
  int kgrp = l >> 4;
  int grow = mbase + w * 16 + lrow;
  int ga = grow < n ? grow : n - 1;
  const float* arow = msg + ((size_t)ga + (size_t)n) * 128;  // msg_tgt row

  s16x8 afrag[4];
#pragma unroll
  for (int kk = 0; kk < 4; ++kk) {
    int k0 = kk * 32 + kgrp * 8;
    float4 p0 = *(const float4*)(arow + k0);
    float4 p1 = *(const float4*)(arow + k0 + 4);
    s16x8 af;
    af[0] = (short)f2bf(p0.x); af[1] = (short)f2bf(p0.y);
    af[2] = (short)f2bf(p0.z); af[3] = (short)f2bf(p0.w);
    af[4] = (short)f2bf(p1.x); af[5] = (short)f2bf(p1.y);
    af[6] = (short)f2bf(p1.z); af[7] = (short)f2bf(p1.w);
    afrag[kk] = af;
  }

  for (int ct = 0; ct < 16; ++ct) {
    int col = ct * 16 + lrow;
    f32x4 acc = {0.f, 0.f, 0.f, 0.f};
#pragma unroll
    for (int kk = 0; kk < 4; ++kk) {
      s16x8 bfrag = *(const s16x8*)(Wb + (size_t)col * 128 + kk * 32 + kgrp * 8);
      acc = __builtin_amdgcn_mfma_f32_16x16x32_bf16(afrag[kk], bfrag, acc, 0, 0, 0);
    }
    int h = ct >> 1;
#pragma unroll
    for (int r = 0; r < 4; ++r) {
      int lr = w * 16 + kgrp * 4 + r;
      int ge = mbase + lr;
      if (ge < n) {
        float p = acc[r];
        float a = att_lds[lr][h];
        out[(size_t)ge * 256 + col] = a * p;
        out[((size_t)ge + (size_t)n) * 256 + col] = p;
      }
    }
  }
}

// ---------------------------------------------------------------------------
extern "C" void kernel_launch(void* const* d_in, const int* in_sizes, int n_in,
                              void* d_out, int out_size, void* d_ws, size_t ws_size,
                              hipStream_t stream) {
  const float* messages = (const float*)d_in[0];
  const float* W        = (const float*)d_in[1];
  const float* a_src    = (const float*)d_in[2];
  const float* a_tgt    = (const float*)d_in[3];
  const int*   index    = (const int*)d_in[4];
  int n = in_sizes[4];  // n_edges = 250000

  char* ws = (char*)d_ws;
  unsigned short* Wb     = (unsigned short*)(ws);             // 65536 B
  unsigned short* wb_cat = (unsigned short*)(ws + 65536);     // 4096 B
  float* denom           = (float*)(ws + 69632);              // 1.6 MB
  float* ex              = (float*)(ws + 69632 + 1600000);    // 8 MB
  float* out = (float*)d_out;

  prep_kernel<<<(NSEG * 8 + 255) / 256, 256, 0, stream>>>(W, a_src, a_tgt, Wb,
                                                          wb_cat, denom);
  score_kernel<<<(n + 63) / 64, 256, 0, stream>>>(messages, index, wb_cat, ex,
                                                  denom, n);
  gemm_kernel<<<(n + 63) / 64, 256, 0, stream>>>(messages, index, Wb, ex, denom,
                                                 out, n);
}

// Round 3
// 213.947 us; speedup vs baseline: 2.1323x; 1.6198x over previous
//
#include <hip/hip_runtime.h>
#include <hip/hip_bf16.h>

#define NSEG 50000

typedef __attribute__((ext_vector_type(4))) float f32x4;
typedef __attribute__((ext_vector_type(8))) short s16x8;

static __device__ __forceinline__ unsigned short f2bf(float f) {
  unsigned int u = __float_as_uint(f);
  u += 0x7fffu + ((u >> 16) & 1u);   // round-to-nearest-even
  return (unsigned short)(u >> 16);
}

static __device__ __forceinline__ s16x8 pack_bf16x8(const float* p) {
  float4 p0 = *(const float4*)(p);
  float4 p1 = *(const float4*)(p + 4);
  s16x8 v;
  v[0] = (short)f2bf(p0.x); v[1] = (short)f2bf(p0.y);
  v[2] = (short)f2bf(p0.z); v[3] = (short)f2bf(p0.w);
  v[4] = (short)f2bf(p1.x); v[5] = (short)f2bf(p1.y);
  v[6] = (short)f2bf(p1.z); v[7] = (short)f2bf(p1.w);
  return v;
}

// ---------------------------------------------------------------------------
// prep: Wb = bf16(W) [256x128].
//       wb_cat[16][128] bf16: rows 0-7 = sum_f W[h*32+f,:]*a_src[h,f] (head h),
//                             rows 8-15 = same with a_tgt.
//       denom = 0.
// ---------------------------------------------------------------------------
__global__ __launch_bounds__(256) void prep_kernel(
    const float* __restrict__ W, const float* __restrict__ a_src,
    const float* __restrict__ a_tgt, unsigned short* __restrict__ Wb,
    unsigned short* __restrict__ wb_cat, float* __restrict__ denom) {
  int t = blockIdx.x * 256 + threadIdx.x;
  if (t < 32768) Wb[t] = f2bf(W[t]);
  if (t < 2048) {
    int row = t >> 7, k = t & 127;
    int h = row & 7;
    const float* a = (row < 8) ? a_src : a_tgt;
    float acc = 0.f;
    for (int f = 0; f < 32; ++f) acc += W[(h * 32 + f) * 128 + k] * a[h * 32 + f];
    wb_cat[t] = f2bf(acc);
  }
  if (t < NSEG * 8) denom[t] = 0.f;
}

// ---------------------------------------------------------------------------
// score: MFMA with A = wb_cat (16 rows x 128 K), B = msg rows (K x 16 edges).
//   ds = wb_cat . msg_src  (rows 0-7 valid = src heads)
//   dt = wb_cat . msg_tgt  (rows 8-15 valid = tgt heads)
// C layout: row = kgrp*4+r (wb_cat row), col = lane&15 (edge).
//   lanes kgrp<2: h = kgrp*4+r;  tgt partner via shfl_xor(dt, 32).
//   leaky_relu, exp, atomicAdd denom, float4 store of ex.
// ---------------------------------------------------------------------------
__global__ __launch_bounds__(256) void score_kernel(
    const float* __restrict__ msg, const int* __restrict__ index,
    const unsigned short* __restrict__ wb_cat, float* __restrict__ ex,
    float* __restrict__ denom, int n) {
  int tid = threadIdx.x;
  int w = tid >> 6, l = tid & 63;
  int lcol = l & 15;   // A row / B col (edge) within tile
  int kgrp = l >> 4;   // k-chunk of 8
  int e0 = blockIdx.x * 64 + w * 16;
  int grow = e0 + lcol;
  int ga = grow < n ? grow : n - 1;
  const float* rs = msg + (size_t)ga * 128;                // msg_src row
  const float* rt = msg + ((size_t)ga + (size_t)n) * 128;  // msg_tgt row

  s16x8 afrag[4];
#pragma unroll
  for (int kk = 0; kk < 4; ++kk)
    afrag[kk] = *(const s16x8*)(wb_cat + lcol * 128 + kk * 32 + kgrp * 8);

  f32x4 ds = {0.f, 0.f, 0.f, 0.f};
  f32x4 dt = {0.f, 0.f, 0.f, 0.f};
#pragma unroll
  for (int kk = 0; kk < 4; ++kk) {
    int k0 = kk * 32 + kgrp * 8;
    s16x8 bs = pack_bf16x8(rs + k0);
    ds = __builtin_amdgcn_mfma_f32_16x16x32_bf16(afrag[kk], bs, ds, 0, 0, 0);
    s16x8 bt = pack_bf16x8(rt + k0);
    dt = __builtin_amdgcn_mfma_f32_16x16x32_bf16(afrag[kk], bt, dt, 0, 0, 0);
  }

  int ge = e0 + lcol;
  f32x4 evv;
#pragma unroll
  for (int r = 0; r < 4; ++r) {
    float tv = __shfl_xor(dt[r], 32);   // lane kgrp -> kgrp+2: dt row h+8
    float s = ds[r] + tv;
    s = s > 0.f ? s : 0.2f * s;         // leaky_relu, NEG_SLOPE=0.2
    evv[r] = __expf(s);
  }
  if (kgrp < 2 && ge < n) {
    int seg = index[ge];
#pragma unroll
    for (int r = 0; r < 4; ++r) atomicAdd(&denom[seg * 8 + kgrp * 4 + r], evv[r]);
    *(f32x4*)(ex + (size_t)ge * 8 + kgrp * 4) = evv;
  }
}

// ---------------------------------------------------------------------------
// gemm: proj_tgt = msg_tgt @ W^T via MFMA with A = Wb (features x K),
// B = msg_tgt (K x edges).  C: row = feature (kgrp*4+r), col = edge (lane&15)
// -> lane holds 4 CONSECUTIVE features of one edge -> float4 stores.
// Block = 64 edges x 256 features; wave w owns features [w*64, w*64+64),
// loads its 16 Wb A-frags once, loops over 4 edge-tiles.
//   out[e]   = att[e,h] * proj    (att = ex / (denom[seg]+1e-16))
//   out[n+e] = proj
// ---------------------------------------------------------------------------
__global__ __launch_bounds__(256) void gemm_kernel(
    const float* __restrict__ msg, const int* __restrict__ index,
    const unsigned short* __restrict__ Wb, const float* __restrict__ ex,
    const float* __restrict__ denom, float* __restrict__ out, int n) {
  __shared__ float att_lds[64][9];
  int tid = threadIdx.x;
  int mbase = blockIdx.x * 64;

  for (int i = tid; i < 512; i += 256) {
    int r = i >> 3, h = i & 7;
    int ge = mbase + r;
    float a = 0.f;
    if (ge < n) {
      int seg = index[ge];
      a = ex[(size_t)ge * 8 + h] / (denom[seg * 8 + h] + 1e-16f);
    }
    att_lds[r][h] = a;
  }
  __syncthreads();

  int w = tid >> 6, l = tid & 63;
  int lcol = l & 15;   // A row (feature within tile) AND B col (edge within tile)
  int kgrp = l >> 4;

  // A-frags: wave w's 4 feature-tiles, loaded once (Wb is L2-resident)
  s16x8 afrag[4][4];
#pragma unroll
  for (int ct = 0; ct < 4; ++ct) {
    int feat = w * 64 + ct * 16 + lcol;
#pragma unroll
    for (int kk = 0; kk < 4; ++kk)
      afrag[ct][kk] = *(const s16x8*)(Wb + (size_t)feat * 128 + kk * 32 + kgrp * 8);
  }

  for (int t = 0; t < 4; ++t) {
    int e0 = mbase + t * 16;
    int grow = e0 + lcol;
    int ga = grow < n ? grow : n - 1;
    const float* brow = msg + ((size_t)ga + (size_t)n) * 128;  // msg_tgt row

    s16x8 bfrag[4];
#pragma unroll
    for (int kk = 0; kk < 4; ++kk) bfrag[kk] = pack_bf16x8(brow + kk * 32 + kgrp * 8);

    int ge = e0 + lcol;
    bool ok = ge < n;
    size_t ob = (size_t)ge * 256;
    size_t pb = ((size_t)ge + (size_t)n) * 256;

#pragma unroll
    for (int ct = 0; ct < 4; ++ct) {
      f32x4 acc = {0.f, 0.f, 0.f, 0.f};
#pragma unroll
      for (int kk = 0; kk < 4; ++kk)
        acc = __builtin_amdgcn_mfma_f32_16x16x32_bf16(afrag[ct][kk], bfrag[kk], acc, 0, 0, 0);
      int f0 = w * 64 + ct * 16 + kgrp * 4;
      if (ok) {
        float a = att_lds[t * 16 + lcol][f0 >> 5];
        f32x4 wv = acc * a;
        __builtin_nontemporal_store(wv, (f32x4*)(out + ob + f0));
        __builtin_nontemporal_store(acc, (f32x4*)(out + pb + f0));
      }
    }
  }
}

// ---------------------------------------------------------------------------
extern "C" void kernel_launch(void* const* d_in, const int* in_sizes, int n_in,
                              void* d_out, int out_size, void* d_ws, size_t ws_size,
                              hipStream_t stream) {
  const float* messages = (const float*)d_in[0];
  const float* W        = (const float*)d_in[1];
  const float* a_src    = (const float*)d_in[2];
  const float* a_tgt    = (const float*)d_in[3];
  const int*   index    = (const int*)d_in[4];
  int n = in_sizes[4];  // n_edges = 250000

  char* ws = (char*)d_ws;
  unsigned short* Wb     = (unsigned short*)(ws);             // 65536 B
  unsigned short* wb_cat = (unsigned short*)(ws + 65536);     // 4096 B
  float* denom           = (float*)(ws + 69632);              // 1.6 MB
  float* ex              = (float*)(ws + 69632 + 1600000);    // 8 MB
  float* out = (float*)d_out;

  prep_kernel<<<(NSEG * 8 + 255) / 256, 256, 0, stream>>>(W, a_src, a_tgt, Wb,
                                                          wb_cat, denom);
  score_kernel<<<(n + 63) / 64, 256, 0, stream>>>(messages, index, wb_cat, ex,
                                                  denom, n);
  gemm_kernel<<<(n + 63) / 64, 256, 0, stream>>>(messages, index, Wb, ex, denom,
                                                 out, n);
}